// Round 6
// baseline (322.433 us; speedup 1.0000x reference)
//
#include <hip/hip_runtime.h>

#define BS 2
#define SEQ 2048
#define HID 1024
#define HEADS 16
#define HDIM 64
#define MTOT (BS * SEQ)  // 4096

typedef __bf16 bf16x8 __attribute__((ext_vector_type(8)));
typedef float floatx4 __attribute__((ext_vector_type(4)));
typedef short short8 __attribute__((ext_vector_type(8)));
typedef unsigned int u32x4 __attribute__((ext_vector_type(4)));
typedef unsigned int u32x2 __attribute__((ext_vector_type(2)));

__device__ __forceinline__ floatx4 mfma16x16x32bf16(short8 a, short8 b, floatx4 c) {
    return __builtin_amdgcn_mfma_f32_16x16x32_bf16(
        __builtin_bit_cast(bf16x8, a), __builtin_bit_cast(bf16x8, b), c, 0, 0, 0);
}

__device__ __forceinline__ unsigned short f2bf(float f) {
    unsigned int u = __builtin_bit_cast(unsigned int, f);
    u += 0x7fffu + ((u >> 16) & 1u);   // RNE
    return (unsigned short)(u >> 16);
}

#define GLOAD_LDS16(gsrc, ldst)                                                   \
    __builtin_amdgcn_global_load_lds(                                             \
        (const __attribute__((address_space(1))) void*)(gsrc),                    \
        (__attribute__((address_space(3))) void*)(ldst), 16, 0, 0)

// fp32 -> bf16 conversion pre-pass: X (4M elems) + 4 weight matrices (1M each).
// dst layout: Xb[4M] Wqb[1M] Wkb[1M] Wvb[1M] Wob[1M]
__global__ __launch_bounds__(256) void cvt5(
    const float* __restrict__ X, const float* __restrict__ Wq,
    const float* __restrict__ Wk, const float* __restrict__ Wv,
    const float* __restrict__ Wo, unsigned short* __restrict__ dst)
{
    const int y = blockIdx.y;
    const float* src = (y == 0) ? X : (y == 1) ? Wq : (y == 2) ? Wk : (y == 3) ? Wv : Wo;
    const size_t base = (y == 0) ? 0 : (size_t)(4u << 20) + (size_t)(y - 1) * (1u << 20);
    const int n4 = (y == 0) ? (1 << 20) : (1 << 18);  // float4 count
    int i = blockIdx.x * 256 + threadIdx.x;
    if (i >= n4) return;
    floatx4 v = *(const floatx4*)(src + (size_t)i * 4);
    unsigned int p0 = (unsigned int)f2bf(v[0]) | ((unsigned int)f2bf(v[1]) << 16);
    unsigned int p1 = (unsigned int)f2bf(v[2]) | ((unsigned int)f2bf(v[3]) << 16);
    u32x2 pk = {p0, p1};
    *(u32x2*)(dst + base + (size_t)i * 4) = pk;
}

// C = X @ W^T + bias.  m97-verified pattern: 128x128 tile, BK=32, 4 waves 2x2,
// global_load_lds width=16, 2-barrier K-loop.
// qkv_mode=1: bf16 out at [z][b][h][s][d]; qkv_mode=0: FP32 out row-major [m][n].
__global__ __launch_bounds__(256) void gemm_bt(
    const unsigned short* __restrict__ X,
    const unsigned short* __restrict__ W0, const unsigned short* __restrict__ W1,
    const unsigned short* __restrict__ W2,
    const float* __restrict__ B0, const float* __restrict__ B1,
    const float* __restrict__ B2,
    unsigned short* __restrict__ out_bf, float* __restrict__ out_f,
    int qkv_mode)
{
    __shared__ __align__(16) unsigned short sA[128 * 32];
    __shared__ __align__(16) unsigned short sB[128 * 32];

    const int tid  = threadIdx.x;
    const int z    = blockIdx.z;
    const unsigned short* W  = (z == 0) ? W0 : (z == 1) ? W1 : W2;
    const float*          Bb = (z == 0) ? B0 : (z == 1) ? B1 : B2;
    const int m0   = blockIdx.x * 128;
    const int n0   = blockIdx.y * 128;
    const int lane = tid & 63, w = tid >> 6;
    const int l16  = lane & 15, grp = lane >> 4;
    const int wm   = w & 1, wn = w >> 1;

    floatx4 acc[4][4];
#pragma unroll
    for (int i = 0; i < 4; ++i)
#pragma unroll
        for (int j = 0; j < 4; ++j) acc[i][j] = (floatx4){0.f, 0.f, 0.f, 0.f};

    auto stage = [&](int kb) {
        const int kcol = kb * 32;
#pragma unroll
        for (int i = 0; i < 2; ++i) {
            int g = tid + i * 256;           // 16B-chunk id 0..511
            int row = g >> 2, c8 = (g & 3) * 8;
            GLOAD_LDS16(X + (size_t)(m0 + row) * HID + kcol + c8, &sA[g * 8]);
            GLOAD_LDS16(W + (size_t)(n0 + row) * HID + kcol + c8, &sB[g * 8]);
        }
    };

    stage(0);
    for (int kb = 0; kb < 32; ++kb) {
        __syncthreads();                       // drains vmcnt: staging visible
        short8 af[4], bfr[4];
#pragma unroll
        for (int t = 0; t < 4; ++t) {
            af[t]  = *(const short8*)&sA[(wm * 64 + t * 16 + l16) * 32 + grp * 8];
            bfr[t] = *(const short8*)&sB[(wn * 64 + t * 16 + l16) * 32 + grp * 8];
        }
        __syncthreads();                       // frag reads done before overwrite
        if (kb + 1 < 32) stage(kb + 1);        // async, overlaps MFMAs
#pragma unroll
        for (int mt = 0; mt < 4; ++mt)
#pragma unroll
            for (int nt = 0; nt < 4; ++nt)
                acc[mt][nt] = mfma16x16x32bf16(af[mt], bfr[nt], acc[mt][nt]);
    }

    // epilogue: C row(m)=grp*4+reg, col(n)=l16 (verified m89 layout)
#pragma unroll
    for (int nt = 0; nt < 4; ++nt) {
        int n = n0 + wn * 64 + nt * 16 + l16;
        float bias = Bb[n];
#pragma unroll
        for (int mt = 0; mt < 4; ++mt) {
#pragma unroll
            for (int r = 0; r < 4; ++r) {
                int m = m0 + wm * 64 + mt * 16 + grp * 4 + r;
                float v = acc[mt][nt][r] + bias;
                if (qkv_mode) {
                    int b = m >> 11, s = m & 2047, hh = n >> 6, d = n & 63;
                    size_t idx = (size_t)z * ((size_t)MTOT * HID) +
                                 ((((size_t)b * HEADS + hh) * SEQ + s) * HDIM + d);
                    out_bf[idx] = f2bf(v);
                } else {
                    out_f[(size_t)m * HID + n] = v;   // FP32 final output
                }
            }
        }
    }
}

// Flash-style attention, one block per (qb, h, b); 4 waves x 16 query rows.
// Block-causal: kv blocks 0..qb attended in full.  Q/K/V layout [b][h][s][d].
// Cross-validated against naive attention (R2==R3 bit-identical output).
__global__ __launch_bounds__(256) void attn_kernel(
    const unsigned short* __restrict__ Qw, const unsigned short* __restrict__ Kw,
    const unsigned short* __restrict__ Vw, unsigned short* __restrict__ X2)
{
    __shared__ __align__(16) unsigned short Qs[64][72];   // +8 pad: 2-way banks (free)
    __shared__ __align__(16) unsigned short Ks[64][72];
    __shared__ __align__(16) unsigned short Vts[64][72];  // V transposed: [d][kv]
    __shared__ __align__(16) unsigned short Ps[4][16][72];

    const int qb = blockIdx.x, h = blockIdx.y, b = blockIdx.z;
    const int tid  = threadIdx.x;
    const int lane = tid & 63, w = tid >> 6;
    const int l16  = lane & 15, grp = lane >> 4;

    const size_t head_off = ((size_t)b * HEADS + h) * SEQ * HDIM;

    {   // load Q tile 64x64
        const unsigned short* src = Qw + head_off + (size_t)qb * 64 * 64;
#pragma unroll
        for (int i = 0; i < 2; ++i) {
            int c = tid + i * 256, row = c >> 3, c8 = (c & 7) * 8;
            *(u32x4*)&Qs[row][c8] = *(const u32x4*)(src + row * 64 + c8);
        }
    }
    __syncthreads();
    short8 qf[2];
    qf[0] = *(const short8*)&Qs[w * 16 + l16][grp * 8];
    qf[1] = *(const short8*)&Qs[w * 16 + l16][grp * 8 + 32];

    floatx4 o[4];
#pragma unroll
    for (int i = 0; i < 4; ++i) o[i] = (floatx4){0.f, 0.f, 0.f, 0.f};
    float mi[4], li[4];
#pragma unroll
    for (int r = 0; r < 4; ++r) { mi[r] = -1e30f; li[r] = 0.f; }

    for (int kb = 0; kb <= qb; ++kb) {
        const unsigned short* ksrc = Kw + head_off + (size_t)kb * 64 * 64;
        const unsigned short* vsrc = Vw + head_off + (size_t)kb * 64 * 64;
#pragma unroll
        for (int i = 0; i < 2; ++i) {
            int c = tid + i * 256, row = c >> 3, c8 = (c & 7) * 8;
            *(u32x4*)&Ks[row][c8] = *(const u32x4*)(ksrc + row * 64 + c8);
            u32x4 vv = *(const u32x4*)(vsrc + row * 64 + c8);
            unsigned short tmp[8];
            *(u32x4*)tmp = vv;
#pragma unroll
            for (int j = 0; j < 8; ++j) Vts[c8 + j][row] = tmp[j];  // transpose
        }
        __syncthreads();   // staging visible

        // S = (Q K^T) * scale; per wave a 16x64 tile as 4 C-frags
        floatx4 sv[4];
#pragma unroll
        for (int nt = 0; nt < 4; ++nt) {
            short8 kf0 = *(const short8*)&Ks[nt * 16 + l16][grp * 8];
            short8 kf1 = *(const short8*)&Ks[nt * 16 + l16][grp * 8 + 32];
            floatx4 zz = (floatx4){0.f, 0.f, 0.f, 0.f};
            zz = mfma16x16x32bf16(qf[0], kf0, zz);
            zz = mfma16x16x32bf16(qf[1], kf1, zz);
            sv[nt] = zz * 0.125f;   // 1/sqrt(64)
        }

        // online softmax; rows grp*4+r, columns spread over 16 lanes of this group
        float alpha[4];
#pragma unroll
        for (int r = 0; r < 4; ++r) {
            float mx = fmaxf(fmaxf(sv[0][r], sv[1][r]), fmaxf(sv[2][r], sv[3][r]));
#pragma unroll
            for (int off = 1; off < 16; off <<= 1)
                mx = fmaxf(mx, __shfl_xor(mx, off, 16));
            float mn = fmaxf(mi[r], mx);
            alpha[r] = __expf(mi[r] - mn);
            mi[r] = mn;
            float rs = 0.f;
#pragma unroll
            for (int nt = 0; nt < 4; ++nt) {
                float p = __expf(sv[nt][r] - mn);
                sv[nt][r] = p;
                rs += p;
            }
#pragma unroll
            for (int off = 1; off < 16; off <<= 1)
                rs += __shfl_xor(rs, off, 16);
            li[r] = li[r] * alpha[r] + rs;
        }

        // P: C-layout -> LDS (bf16) -> A-layout
#pragma unroll
        for (int nt = 0; nt < 4; ++nt)
#pragma unroll
            for (int r = 0; r < 4; ++r)
                Ps[w][grp * 4 + r][nt * 16 + l16] = f2bf(sv[nt][r]);
        __syncthreads();   // P visible

#pragma unroll
        for (int dt = 0; dt < 4; ++dt)
#pragma unroll
            for (int r = 0; r < 4; ++r) o[dt][r] *= alpha[r];

#pragma unroll
        for (int ks = 0; ks < 2; ++ks) {
            short8 pf = *(const short8*)&Ps[w][l16][ks * 32 + grp * 8];
#pragma unroll
            for (int dt = 0; dt < 4; ++dt) {
                short8 vf = *(const short8*)&Vts[dt * 16 + l16][ks * 32 + grp * 8];
                o[dt] = mfma16x16x32bf16(pf, vf, o[dt]);
            }
        }
        __syncthreads();   // all Ks/Vts/Ps reads done before next staging
    }

    // write O / l  ->  X2 [b][s][h][d] (= row-major [4096][1024] GEMM input)
    float inv[4];
#pragma unroll
    for (int r = 0; r < 4; ++r) inv[r] = 1.0f / li[r];
#pragma unroll
    for (int dt = 0; dt < 4; ++dt)
#pragma unroll
        for (int r = 0; r < 4; ++r) {
            int srow = qb * 64 + w * 16 + grp * 4 + r;
            int col  = h * HDIM + dt * 16 + l16;
            X2[((size_t)b * SEQ + srow) * HID + col] = f2bf(o[dt][r] * inv[r]);
        }
}

extern "C" void kernel_launch(void* const* d_in, const int* in_sizes, int n_in,
                              void* d_out, int out_size, void* d_ws, size_t ws_size,
                              hipStream_t stream) {
    // Dict order confirmed by R5 bisection (in_sizes[0]==4M -> hidden_states first).
    // Keep the alphabetical fallback as a safety net.
    int iX, iWq, ibq, iWk, ibk, iWv, ibv, iWo, ibo;
    if (in_sizes[0] == MTOT * HID) {
        iX = 0; iWq = 1; ibq = 2; iWk = 3; ibk = 4; iWv = 5; ibv = 6; iWo = 7; ibo = 8;
    } else {
        iWk = 0; iWo = 1; iWq = 2; iWv = 3; ibk = 4; ibo = 5; ibq = 6; ibv = 7; iX = 8;
    }
    const float* X  = (const float*)d_in[iX];
    const float* Wq = (const float*)d_in[iWq];
    const float* bq = (const float*)d_in[ibq];
    const float* Wk = (const float*)d_in[iWk];
    const float* bk = (const float*)d_in[ibk];
    const float* Wv = (const float*)d_in[iWv];
    const float* bv = (const float*)d_in[ibv];
    const float* Wo = (const float*)d_in[iWo];
    const float* bo = (const float*)d_in[ibo];
    float* out = (float*)d_out;                // reference output dtype = float32

    unsigned short* ws = (unsigned short*)d_ws;
    const size_t T = (size_t)MTOT * HID;       // 4M elements
    unsigned short* qw  = ws;                  // [b][h][s][d]
    unsigned short* kw  = ws + T;
    unsigned short* vw  = ws + 2 * T;
    unsigned short* x2  = ws + 3 * T;          // attention out, [b][s][h][d]
    unsigned short* Xb  = ws + 4 * T;          // bf16 X
    unsigned short* Wqb = Xb + T;              // bf16 weights, 1M each
    unsigned short* Wkb = Wqb + (size_t)HID * HID;
    unsigned short* Wvb = Wkb + (size_t)HID * HID;
    unsigned short* Wob = Wvb + (size_t)HID * HID;

    // 0) fp32 -> bf16 conversion of X and weights
    cvt5<<<dim3(4096, 5), 256, 0, stream>>>(X, Wq, Wk, Wv, Wo, Xb);
    // 1) Q/K/V projections (z picks weight/bias/output slot) -> bf16 workspace
    gemm_bt<<<dim3(32, 8, 3), 256, 0, stream>>>(Xb, Wqb, Wkb, Wvb, bq, bk, bv,
                                                ws, nullptr, 1);
    // 2) block-causal flash attention
    attn_kernel<<<dim3(32, 16, 2), 256, 0, stream>>>(qw, kw, vw, x2);
    // 3) output projection -> d_out (FP32)
    gemm_bt<<<dim3(32, 8, 1), 256, 0, stream>>>(x2, Wob, Wob, Wob, bo, bo, bo,
                                                nullptr, out, 0);
}

// Round 8
// 250.240 us; speedup vs baseline: 1.2885x; 1.2885x over previous
//
#include <hip/hip_runtime.h>

#define BS 2
#define SEQ 2048
#define HID 1024
#define HEADS 16
#define HDIM 64
#define MTOT (BS * SEQ)  // 4096

typedef __bf16 bf16x8 __attribute__((ext_vector_type(8)));
typedef float floatx4 __attribute__((ext_vector_type(4)));
typedef short short8 __attribute__((ext_vector_type(8)));
typedef unsigned short u16x4 __attribute__((ext_vector_type(4)));
typedef unsigned int u32x2 __attribute__((ext_vector_type(2)));

__device__ __forceinline__ floatx4 mfma16x16x32bf16(short8 a, short8 b, floatx4 c) {
    return __builtin_amdgcn_mfma_f32_16x16x32_bf16(
        __builtin_bit_cast(bf16x8, a), __builtin_bit_cast(bf16x8, b), c, 0, 0, 0);
}

__device__ __forceinline__ unsigned short f2bf(float f) {
    unsigned int u = __builtin_bit_cast(unsigned int, f);
    u += 0x7fffu + ((u >> 16) & 1u);   // RNE
    return (unsigned short)(u >> 16);
}

#define GLOAD_LDS16(gsrc, ldst)                                                   \
    __builtin_amdgcn_global_load_lds(                                             \
        (const __attribute__((address_space(1))) void*)(gsrc),                    \
        (__attribute__((address_space(3))) void*)(ldst), 16, 0, 0)

// fp32 -> bf16 conversion pre-pass: X (4M) + Wq,Wk,Wv,Wo (1M each).
__global__ __launch_bounds__(256) void cvt5(
    const float* __restrict__ X, const float* __restrict__ Wq,
    const float* __restrict__ Wk, const float* __restrict__ Wv,
    const float* __restrict__ Wo, unsigned short* __restrict__ dst)
{
    const int y = blockIdx.y;
    const float* src = (y == 0) ? X : (y == 1) ? Wq : (y == 2) ? Wk : (y == 3) ? Wv : Wo;
    const size_t base = (y == 0) ? 0 : (size_t)(4u << 20) + (size_t)(y - 1) * (1u << 20);
    const int n4 = (y == 0) ? (1 << 20) : (1 << 18);
    int i = blockIdx.x * 256 + threadIdx.x;
    if (i >= n4) return;
    floatx4 v = *(const floatx4*)(src + (size_t)i * 4);
    unsigned int p0 = (unsigned int)f2bf(v[0]) | ((unsigned int)f2bf(v[1]) << 16);
    unsigned int p1 = (unsigned int)f2bf(v[2]) | ((unsigned int)f2bf(v[3]) << 16);
    u32x2 pk = {p0, p1};
    *(u32x2*)(dst + base + (size_t)i * 4) = pk;
}

// C = X @ W^T + bias, m97 structure (128x128, BK=32, global_load_lds w=16).
// MODE 0: fp32 out row-major [m][n] (out-projection).
// MODE 1: QKV.  z<2 (Q,K): operand-swapped MFMA -> D[n][m]; lane packs 4
//   consecutive d -> 8B bf16 stores at [b][h][s][d], out offset z*T.
//   z==2 (V): normal MFMA; lane packs 4 consecutive s -> 8B stores at
//   2*T + [b][h][d][s] (pre-transposed V for the attention B-frags).
template <int MODE>
__global__ __launch_bounds__(256) void gemm_bt(
    const unsigned short* __restrict__ X,
    const unsigned short* __restrict__ W0, const unsigned short* __restrict__ W1,
    const unsigned short* __restrict__ W2,
    const float* __restrict__ B0, const float* __restrict__ B1,
    const float* __restrict__ B2,
    unsigned short* __restrict__ out_bf, float* __restrict__ out_f)
{
    __shared__ __align__(16) unsigned short sA[128 * 32];
    __shared__ __align__(16) unsigned short sB[128 * 32];

    const int tid  = threadIdx.x;
    const int z    = blockIdx.z;
    const unsigned short* W  = (z == 0) ? W0 : (z == 1) ? W1 : W2;
    const float*          Bb = (z == 0) ? B0 : (z == 1) ? B1 : B2;
    const int m0   = blockIdx.x * 128;
    const int n0   = blockIdx.y * 128;
    const int lane = tid & 63, w = tid >> 6;
    const int l16  = lane & 15, grp = lane >> 4;
    const int wm   = w & 1, wn = w >> 1;

    floatx4 acc[4][4];
#pragma unroll
    for (int i = 0; i < 4; ++i)
#pragma unroll
        for (int j = 0; j < 4; ++j) acc[i][j] = (floatx4){0.f, 0.f, 0.f, 0.f};

    auto stage = [&](int kb) {
        const int kcol = kb * 32;
#pragma unroll
        for (int i = 0; i < 2; ++i) {
            int g = tid + i * 256;
            int row = g >> 2, c8 = (g & 3) * 8;
            GLOAD_LDS16(X + (size_t)(m0 + row) * HID + kcol + c8, &sA[g * 8]);
            GLOAD_LDS16(W + (size_t)(n0 + row) * HID + kcol + c8, &sB[g * 8]);
        }
    };

    const bool swapT = (MODE == 1) && (z < 2);
    stage(0);
    for (int kb = 0; kb < 32; ++kb) {
        __syncthreads();
        short8 af[4], bfr[4];
#pragma unroll
        for (int t = 0; t < 4; ++t) {
            af[t]  = *(const short8*)&sA[(wm * 64 + t * 16 + l16) * 32 + grp * 8];
            bfr[t] = *(const short8*)&sB[(wn * 64 + t * 16 + l16) * 32 + grp * 8];
        }
        __syncthreads();
        if (kb + 1 < 32) stage(kb + 1);
        if (swapT) {
#pragma unroll
            for (int mt = 0; mt < 4; ++mt)
#pragma unroll
                for (int nt = 0; nt < 4; ++nt)
                    acc[mt][nt] = mfma16x16x32bf16(bfr[nt], af[mt], acc[mt][nt]);
        } else {
#pragma unroll
            for (int mt = 0; mt < 4; ++mt)
#pragma unroll
                for (int nt = 0; nt < 4; ++nt)
                    acc[mt][nt] = mfma16x16x32bf16(af[mt], bfr[nt], acc[mt][nt]);
        }
    }

    if (MODE == 0) {
        // D[row=m: grp*4+r][col=n: l16] (m89-verified) -> fp32 [m][n]
#pragma unroll
        for (int nt = 0; nt < 4; ++nt) {
            int n = n0 + wn * 64 + nt * 16 + l16;
            float bias = Bb[n];
#pragma unroll
            for (int mt = 0; mt < 4; ++mt)
#pragma unroll
                for (int r = 0; r < 4; ++r) {
                    int m = m0 + wm * 64 + mt * 16 + grp * 4 + r;
                    out_f[(size_t)m * HID + n] = acc[mt][nt][r] + bias;
                }
        }
    } else if (z < 2) {
        // swapped: D[row=n: grp*4+r][col=m: l16] -> bf16 [b][h][s][d], 8B packed
        const size_t outz = (size_t)z * ((size_t)MTOT * HID);
        const int hidx = (n0 + wn * 64) >> 6;
#pragma unroll
        for (int nt = 0; nt < 4; ++nt) {
            int dbase = nt * 16 + grp * 4;
            floatx4 b4 = *(const floatx4*)&Bb[n0 + wn * 64 + dbase];
#pragma unroll
            for (int mt = 0; mt < 4; ++mt) {
                int m = m0 + wm * 64 + mt * 16 + l16;
                int bidx = m >> 11, s = m & (SEQ - 1);
                u16x4 pk;
#pragma unroll
                for (int r = 0; r < 4; ++r) pk[r] = f2bf(acc[mt][nt][r] + b4[r]);
                *(u16x4*)&out_bf[outz +
                    ((((size_t)bidx * HEADS + hidx) * SEQ + s) * HDIM + dbase)] = pk;
            }
        }
    } else {
        // normal: D[row=m(s): grp*4+r][col=n(d): l16] -> bf16 V^T [b][h][d][s]
        // at workspace slot 2*T  (R7 BUG: this offset was missing -> V stayed
        // 0xAA-poisoned and the V^T stores raced over Q)
        const size_t outz = (size_t)2 * ((size_t)MTOT * HID);
        const int hidx = (n0 + wn * 64) >> 6;
#pragma unroll
        for (int nt = 0; nt < 4; ++nt) {
            int d = nt * 16 + l16;
            float bias = Bb[n0 + wn * 64 + d];
#pragma unroll
            for (int mt = 0; mt < 4; ++mt) {
                int mbase = m0 + wm * 64 + mt * 16 + grp * 4;
                int bidx = mbase >> 11, sbase = mbase & (SEQ - 1);
                u16x4 pk;
#pragma unroll
                for (int r = 0; r < 4; ++r) pk[r] = f2bf(acc[mt][nt][r] + bias);
                *(u16x4*)&out_bf[outz +
                    ((((size_t)bidx * HEADS + hidx) * HDIM + d) * SEQ + sbase)] = pk;
            }
        }
    }
}

// Barrier-free flash attention.  Workgroup = (qb-pair j/31-j, h, b): waves 0,1
// -> q-block j, waves 2,3 -> q-block 31-j (uniform 33 kv-iters per workgroup).
// Each wave owns 32 q-rows; all fragments loaded directly from global (L1/L2
// serve the K/V re-reads); P round-trips through a wave-PRIVATE LDS slab (no
// __syncthreads; same-wave DS ops are ordered).  Q,K: [b][h][s][d]; V: [b][h][d][s].
__global__ __launch_bounds__(256) void attn_kernel(
    const unsigned short* __restrict__ Qw, const unsigned short* __restrict__ Kw,
    const unsigned short* __restrict__ VTw, unsigned short* __restrict__ X2)
{
    __shared__ __align__(16) unsigned short Ps[4][32][72];  // 144B rows: b128-aligned

    const int pairIdx = blockIdx.x;            // 0..15
    const int h = blockIdx.y, b = blockIdx.z;
    const int tid  = threadIdx.x;
    const int lane = tid & 63, w = tid >> 6;
    const int l16  = lane & 15, grp = lane >> 4;

    const int qblk = (w < 2) ? pairIdx : (31 - pairIdx);
    const int nkb  = qblk + 1;
    const int q0   = qblk * 64 + (w & 1) * 32;

    const size_t head = ((size_t)b * HEADS + h) * (size_t)SEQ * HDIM;

    short8 qf[2][2];   // [mt][ks] A-frags, loaded once
#pragma unroll
    for (int mt = 0; mt < 2; ++mt)
#pragma unroll
        for (int ks = 0; ks < 2; ++ks)
            qf[mt][ks] = *(const short8*)(Qw + head +
                (size_t)(q0 + mt * 16 + l16) * HDIM + ks * 32 + grp * 8);

    floatx4 o[2][4];
    float mi[2][4], li[2][4];
#pragma unroll
    for (int mt = 0; mt < 2; ++mt)
#pragma unroll
        for (int i = 0; i < 4; ++i) {
            o[mt][i] = (floatx4){0.f, 0.f, 0.f, 0.f};
            mi[mt][i] = -1e30f; li[mt][i] = 0.f;
        }

    for (int kb = 0; kb < nkb; ++kb) {
        const unsigned short* kbase = Kw + head + (size_t)kb * 64 * HDIM;
        const unsigned short* vbase = VTw + head + (size_t)kb * 64;
        short8 kf[4][2], vf[4][2];
#pragma unroll
        for (int nt = 0; nt < 4; ++nt)
#pragma unroll
            for (int ks = 0; ks < 2; ++ks) {
                kf[nt][ks] = *(const short8*)(kbase +
                    (size_t)(nt * 16 + l16) * HDIM + ks * 32 + grp * 8);
                vf[nt][ks] = *(const short8*)(vbase +
                    (size_t)(nt * 16 + l16) * SEQ + ks * 32 + grp * 8);
            }

        floatx4 sv[2][4];
#pragma unroll
        for (int mt = 0; mt < 2; ++mt)
#pragma unroll
            for (int nt = 0; nt < 4; ++nt) {
                floatx4 zz = (floatx4){0.f, 0.f, 0.f, 0.f};
                zz = mfma16x16x32bf16(qf[mt][0], kf[nt][0], zz);
                zz = mfma16x16x32bf16(qf[mt][1], kf[nt][1], zz);
                sv[mt][nt] = zz * 0.125f;       // 1/sqrt(64)
            }

#pragma unroll
        for (int mt = 0; mt < 2; ++mt) {
            float alpha[4];
#pragma unroll
            for (int r = 0; r < 4; ++r) {
                float mx = fmaxf(fmaxf(sv[mt][0][r], sv[mt][1][r]),
                                 fmaxf(sv[mt][2][r], sv[mt][3][r]));
#pragma unroll
                for (int off = 1; off < 16; off <<= 1)
                    mx = fmaxf(mx, __shfl_xor(mx, off, 16));
                float mn = fmaxf(mi[mt][r], mx);
                alpha[r] = __expf(mi[mt][r] - mn);
                mi[mt][r] = mn;
                float rs = 0.f;
#pragma unroll
                for (int nt = 0; nt < 4; ++nt) {
                    float p = __expf(sv[mt][nt][r] - mn);
                    sv[mt][nt][r] = p;
                    rs += p;
                }
#pragma unroll
                for (int off = 1; off < 16; off <<= 1)
                    rs += __shfl_xor(rs, off, 16);
                li[mt][r] = li[mt][r] * alpha[r] + rs;
            }
#pragma unroll
            for (int nt = 0; nt < 4; ++nt)
#pragma unroll
                for (int r = 0; r < 4; ++r)
                    Ps[w][mt * 16 + grp * 4 + r][nt * 16 + l16] = f2bf(sv[mt][nt][r]);
#pragma unroll
            for (int dt = 0; dt < 4; ++dt)
#pragma unroll
                for (int r = 0; r < 4; ++r) o[mt][dt][r] *= alpha[r];
        }

        // wave-private round-trip: same-wave DS ordering + lgkmcnt suffices
#pragma unroll
        for (int ks = 0; ks < 2; ++ks)
#pragma unroll
            for (int mt = 0; mt < 2; ++mt) {
                short8 pf = *(const short8*)&Ps[w][mt * 16 + l16][ks * 32 + grp * 8];
#pragma unroll
                for (int dt = 0; dt < 4; ++dt)
                    o[mt][dt] = mfma16x16x32bf16(pf, vf[dt][ks], o[mt][dt]);
            }
    }

    // O / l  ->  X2 [b][s][h*64+d]
#pragma unroll
    for (int mt = 0; mt < 2; ++mt) {
        float inv[4];
#pragma unroll
        for (int r = 0; r < 4; ++r) inv[r] = 1.0f / li[mt][r];
#pragma unroll
        for (int dt = 0; dt < 4; ++dt)
#pragma unroll
            for (int r = 0; r < 4; ++r) {
                int srow = q0 + mt * 16 + grp * 4 + r;
                int col  = h * HDIM + dt * 16 + l16;
                X2[((size_t)b * SEQ + srow) * HID + col] = f2bf(o[mt][dt][r] * inv[r]);
            }
    }
}

extern "C" void kernel_launch(void* const* d_in, const int* in_sizes, int n_in,
                              void* d_out, int out_size, void* d_ws, size_t ws_size,
                              hipStream_t stream) {
    // dict order confirmed (R5/R6); alphabetical fallback kept as safety net
    int iX, iWq, ibq, iWk, ibk, iWv, ibv, iWo, ibo;
    if (in_sizes[0] == MTOT * HID) {
        iX = 0; iWq = 1; ibq = 2; iWk = 3; ibk = 4; iWv = 5; ibv = 6; iWo = 7; ibo = 8;
    } else {
        iWk = 0; iWo = 1; iWq = 2; iWv = 3; ibk = 4; ibo = 5; ibq = 6; ibv = 7; iX = 8;
    }
    const float* X  = (const float*)d_in[iX];
    const float* Wq = (const float*)d_in[iWq];
    const float* bq = (const float*)d_in[ibq];
    const float* Wk = (const float*)d_in[iWk];
    const float* bk = (const float*)d_in[ibk];
    const float* Wv = (const float*)d_in[iWv];
    const float* bv = (const float*)d_in[ibv];
    const float* Wo = (const float*)d_in[iWo];
    const float* bo = (const float*)d_in[ibo];
    float* out = (float*)d_out;                // fp32 output (confirmed R6)

    unsigned short* ws = (unsigned short*)d_ws;
    const size_t T = (size_t)MTOT * HID;       // 4M elements
    unsigned short* qw  = ws;                  // Q  [b][h][s][d]
    unsigned short* kw  = ws + T;              // K  [b][h][s][d]
    unsigned short* vtw = ws + 2 * T;          // V^T[b][h][d][s]
    unsigned short* x2  = ws + 3 * T;          // attn out [b][s][hid]
    unsigned short* Xb  = ws + 4 * T;
    unsigned short* Wqb = Xb + T;
    unsigned short* Wkb = Wqb + (size_t)HID * HID;
    unsigned short* Wvb = Wkb + (size_t)HID * HID;
    unsigned short* Wob = Wvb + (size_t)HID * HID;

    // 0) fp32 -> bf16
    cvt5<<<dim3(4096, 5), 256, 0, stream>>>(X, Wq, Wk, Wv, Wo, Xb);
    // 1) QKV projections: z=0 Q, z=1 K (swapped-MFMA epilogue), z=2 V^T
    gemm_bt<1><<<dim3(32, 8, 3), 256, 0, stream>>>(
        Xb, Wqb, Wkb, Wvb, bq, bk, bv, qw, nullptr);
    // 2) barrier-free block-causal flash attention
    attn_kernel<<<dim3(16, HEADS, BS), 256, 0, stream>>>(qw, kw, vtw, x2);
    // 3) output projection -> d_out (fp32)
    gemm_bt<0><<<dim3(32, 8, 1), 256, 0, stream>>>(
        x2, Wob, Wob, Wob, bo, bo, bo, nullptr, out);
}